// Round 3
// baseline (1642.993 us; speedup 1.0000x reference)
//
#include <hip/hip_runtime.h>

// GCMCGraphConv: out[d] = ci[d] * sum_{e: dst[e]==d} weight[node_ids[src[e]]] * cj[src[e]]
// N_SRC = N_DST = 100000, N_EDGES = 3.2M, OUT_DIM = 64.
//
// Strategy: coarse-bin edges by dst>>7 (128 dsts/bin -> 32KB LDS accumulator),
// then one block per bin accumulates with LDS fp32 atomics and writes the bin
// out once, fused with the ci scale. No global fp32 atomics, no fine-grained
// random 4B scatter (packed edges written in ~168B per-bin runs).

#define OUT_DIM 64
#define BIN_BITS 7
#define BIN_SIZE 128            // dsts per bin; LDS accum = 128*64*4B = 32 KiB
#define MAX_BINS 1024           // n_dst <= MAX_BINS*BIN_SIZE = 131072
#define CHUNK 32768             // edges per block in hist/scatter passes

// ---- K1: per-bin edge counts ----
__global__ void __launch_bounds__(1024) gcmc_bin_hist(
    const int* __restrict__ dst_idx, int* __restrict__ bin_cnt,
    int n_edges, int nbins) {
  __shared__ int h[MAX_BINS];
  for (int b = threadIdx.x; b < nbins; b += blockDim.x) h[b] = 0;
  __syncthreads();
  const int e0 = blockIdx.x * CHUNK;
  const int e1 = min(e0 + CHUNK, n_edges);
  for (int e = e0 + threadIdx.x; e < e1; e += blockDim.x)
    atomicAdd(&h[dst_idx[e] >> BIN_BITS], 1);
  __syncthreads();
  for (int b = threadIdx.x; b < nbins; b += blockDim.x)
    if (h[b]) atomicAdd(&bin_cnt[b], h[b]);
}

// ---- K2: exclusive scan of bin counts (nbins <= 1024, single block) ----
__global__ void __launch_bounds__(1024) gcmc_bin_scan(
    const int* __restrict__ cnt, int* __restrict__ off, int* __restrict__ pos,
    int n) {
  __shared__ int lds[MAX_BINS];
  const int tid = threadIdx.x;
  const int v = (tid < n) ? cnt[tid] : 0;
  lds[tid] = v;
  __syncthreads();
#pragma unroll
  for (int d = 1; d < MAX_BINS; d <<= 1) {
    const int t = (tid >= d) ? lds[tid - d] : 0;
    __syncthreads();
    lds[tid] += t;
    __syncthreads();
  }
  if (tid < n) {
    off[tid] = lds[tid] - v;
    pos[tid] = lds[tid] - v;
  }
  if (tid == 0) off[n] = lds[MAX_BINS - 1];  // total (entries past n are 0)
}

// ---- K3: scatter packed edges into bin-grouped order ----
// pack = (local_dst << 20) | src   (requires n_src < 2^20, local_dst < 2^12)
__global__ void __launch_bounds__(1024) gcmc_bin_scatter(
    const int* __restrict__ dst_idx, const int* __restrict__ src_idx,
    int* __restrict__ bin_pos, unsigned int* __restrict__ edges,
    int n_edges, int nbins) {
  __shared__ int h[MAX_BINS];
  for (int b = threadIdx.x; b < nbins; b += blockDim.x) h[b] = 0;
  __syncthreads();
  const int e0 = blockIdx.x * CHUNK;
  const int e1 = min(e0 + CHUNK, n_edges);
  for (int e = e0 + threadIdx.x; e < e1; e += blockDim.x)
    atomicAdd(&h[dst_idx[e] >> BIN_BITS], 1);
  __syncthreads();
  // reserve contiguous global space per (block, bin); h[b] becomes the cursor
  for (int b = threadIdx.x; b < nbins; b += blockDim.x) {
    const int c = h[b];
    h[b] = c ? atomicAdd(&bin_pos[b], c) : 0;
  }
  __syncthreads();
  for (int e = e0 + threadIdx.x; e < e1; e += blockDim.x) {
    const int d = dst_idx[e];
    const int bin = d >> BIN_BITS;
    const int p = atomicAdd(&h[bin], 1);
    edges[p] = ((unsigned)(d & (BIN_SIZE - 1)) << 20) | (unsigned)src_idx[e];
  }
}

// ---- K4: one block per bin: LDS accumulate + fused ci-scale writeout ----
__global__ void __launch_bounds__(512) gcmc_bin_accum(
    const unsigned int* __restrict__ edges, const int* __restrict__ bin_off,
    const int* __restrict__ node_ids, const float* __restrict__ cj,
    const float* __restrict__ weight, const float* __restrict__ ci,
    float* __restrict__ out, int n_dst) {
  __shared__ float acc[BIN_SIZE * OUT_DIM];
  const int tid = threadIdx.x;
  for (int i = tid; i < BIN_SIZE * OUT_DIM; i += blockDim.x) acc[i] = 0.f;
  __syncthreads();

  const int bin = blockIdx.x;
  const int start = bin_off[bin];
  const int end = bin_off[bin + 1];
  const int lane = tid & 63;
  const int wid = tid >> 6;
  const int nw = blockDim.x >> 6;

  for (int base = start + wid * 64; base < end; base += nw * 64) {
    const int m = min(64, end - base);
    unsigned pk = 0;
    int row = 0;
    float c = 0.f;
    if (lane < m) {
      pk = edges[base + lane];
      const int s = (int)(pk & 0xFFFFFu);
      row = node_ids[s];
      c = cj[s];
    }
    if (m == 64) {
#pragma unroll 8
      for (int k = 0; k < 64; ++k) {
        const int r = __shfl(row, k);
        const float cc = __shfl(c, k);
        const int ld = (int)((unsigned)__shfl((int)pk, k) >> 20);
        const float w = weight[r * OUT_DIM + lane];
        atomicAdd(&acc[ld * OUT_DIM + lane], w * cc);
      }
    } else {
      for (int k = 0; k < m; ++k) {
        const int r = __shfl(row, k);
        const float cc = __shfl(c, k);
        const int ld = (int)((unsigned)__shfl((int)pk, k) >> 20);
        const float w = weight[r * OUT_DIM + lane];
        atomicAdd(&acc[ld * OUT_DIM + lane], w * cc);
      }
    }
  }
  __syncthreads();

  const int gbase = bin * BIN_SIZE;
  for (int i = tid; i < BIN_SIZE * OUT_DIM; i += blockDim.x) {
    const int r = gbase + (i >> 6);
    if (r < n_dst) out[r * OUT_DIM + (i & 63)] = acc[i] * ci[r];
  }
}

extern "C" void kernel_launch(void* const* d_in, const int* in_sizes, int n_in,
                              void* d_out, int out_size, void* d_ws, size_t ws_size,
                              hipStream_t stream) {
  const int* node_ids = (const int*)d_in[0];
  const int* src_idx  = (const int*)d_in[1];
  const int* dst_idx  = (const int*)d_in[2];
  const float* cj     = (const float*)d_in[3];
  const float* ci     = (const float*)d_in[4];
  const float* weight = (const float*)d_in[5];
  float* out = (float*)d_out;

  const int n_edges = in_sizes[1];
  const int n_dst = out_size / OUT_DIM;
  const int nbins = (n_dst + BIN_SIZE - 1) >> BIN_BITS;  // 782 for 100k

  // ws layout (ints): bin_cnt[nbins] | bin_off[nbins+1] | bin_pos[nbins] | edges[n_edges]
  int* bin_cnt = (int*)d_ws;
  int* bin_off = bin_cnt + nbins;
  int* bin_pos = bin_off + (nbins + 1);
  unsigned int* edges = (unsigned int*)(bin_pos + nbins);

  hipMemsetAsync(bin_cnt, 0, (size_t)nbins * sizeof(int), stream);

  const int nblk = (n_edges + CHUNK - 1) / CHUNK;  // 98
  gcmc_bin_hist<<<nblk, 1024, 0, stream>>>(dst_idx, bin_cnt, n_edges, nbins);
  gcmc_bin_scan<<<1, 1024, 0, stream>>>(bin_cnt, bin_off, bin_pos, nbins);
  gcmc_bin_scatter<<<nblk, 1024, 0, stream>>>(dst_idx, src_idx, bin_pos, edges,
                                              n_edges, nbins);
  gcmc_bin_accum<<<nbins, 512, 0, stream>>>(edges, bin_off, node_ids, cj,
                                            weight, ci, out, n_dst);
}

// Round 5
// 1530.882 us; speedup vs baseline: 1.0732x; 1.0732x over previous
//
#include <hip/hip_runtime.h>

// GCMCGraphConv: out[d] = ci[d] * sum_{e: dst[e]==d} weight[node_ids[src[e]]] * cj[src[e]]
// N_SRC = N_DST = 100000, N_EDGES = 3.2M, OUT_DIM = 64.
//
// Pipeline (ws-fitting path):
//   K0 wprime : W'[s] = weight[node_ids[s]] * cj[s]           (hoists per-edge gathers)
//   K1 hist   : per-bin edge counts (bin = dst >> 7)
//   K2 scan   : exclusive scan of bin counts (782 bins, 1 block)
//   K3 scatter: pack (local_dst, src) into bin-grouped order
//   K4 accum  : one block per bin; readlane-broadcast edges; coalesced W' row
//               gather + conflict-free LDS f32 atomics; fused ci-scale writeout.
// Fallback path (ws too small): global-atomic edge scatter (proven R1).

#define OUT_DIM 64
#define BIN_BITS 7
#define BIN_SIZE 128            // dsts per bin
#define MAX_BINS 1024           // supports n_dst <= 131072

// ---- K0: W'[s][:] = weight[node_ids[s]][:] * cj[s] ----
__global__ void __launch_bounds__(256) gcmc_wprime(
    const int* __restrict__ node_ids, const float* __restrict__ cj,
    const float4* __restrict__ weight4, float4* __restrict__ wp4, int n_src) {
  const int i = blockIdx.x * 256 + threadIdx.x;   // float4 index
  if (i >= n_src * (OUT_DIM / 4)) return;
  const int s = i >> 4;
  const float c = cj[s];
  const int r = node_ids[s];
  float4 w = weight4[r * (OUT_DIM / 4) + (i & 15)];
  w.x *= c; w.y *= c; w.z *= c; w.w *= c;
  wp4[i] = w;
}

// ---- K1: per-bin histogram ----
__global__ void __launch_bounds__(512) gcmc_hist(
    const int* __restrict__ dst_idx, int* __restrict__ bin_cnt,
    int n_edges, int nbins) {
  __shared__ int h[MAX_BINS];
  for (int b = threadIdx.x; b < nbins; b += 512) h[b] = 0;
  __syncthreads();
  for (int e = blockIdx.x * 512 + threadIdx.x; e < n_edges; e += gridDim.x * 512)
    atomicAdd(&h[dst_idx[e] >> BIN_BITS], 1);
  __syncthreads();
  for (int b = threadIdx.x; b < nbins; b += 512) {
    const int c = h[b];
    if (c) atomicAdd(&bin_cnt[b], c);
  }
}

// ---- K2: exclusive scan (nbins <= 1024, single block) ----
__global__ void __launch_bounds__(1024) gcmc_scan(
    const int* __restrict__ cnt, int* __restrict__ off, int* __restrict__ pos,
    int n) {
  __shared__ int lds[MAX_BINS];
  const int tid = threadIdx.x;
  const int v = (tid < n) ? cnt[tid] : 0;
  lds[tid] = v;
  __syncthreads();
#pragma unroll
  for (int d = 1; d < MAX_BINS; d <<= 1) {
    const int t = (tid >= d) ? lds[tid - d] : 0;
    __syncthreads();
    lds[tid] += t;
    __syncthreads();
  }
  if (tid < n) {
    off[tid] = lds[tid] - v;
    pos[tid] = lds[tid] - v;
  }
  if (tid == 0) off[n] = lds[MAX_BINS - 1];
}

// ---- K3: scatter packed edges into bin-grouped order ----
// pack = (local_dst << 20) | src   (n_src < 2^20)
__global__ void __launch_bounds__(512) gcmc_scatter(
    const int* __restrict__ dst_idx, const int* __restrict__ src_idx,
    int* __restrict__ bin_pos, unsigned int* __restrict__ edges,
    int n_edges, int nbins) {
  __shared__ int h[MAX_BINS];
  for (int b = threadIdx.x; b < nbins; b += 512) h[b] = 0;
  __syncthreads();
  for (int e = blockIdx.x * 512 + threadIdx.x; e < n_edges; e += gridDim.x * 512)
    atomicAdd(&h[dst_idx[e] >> BIN_BITS], 1);
  __syncthreads();
  for (int b = threadIdx.x; b < nbins; b += 512) {
    const int c = h[b];
    h[b] = c ? atomicAdd(&bin_pos[b], c) : 0;
  }
  __syncthreads();
  for (int e = blockIdx.x * 512 + threadIdx.x; e < n_edges; e += gridDim.x * 512) {
    const int d = dst_idx[e];
    const int p = atomicAdd(&h[d >> BIN_BITS], 1);
    edges[p] = ((unsigned)(d & (BIN_SIZE - 1)) << 20) | (unsigned)src_idx[e];
  }
}

// ---- K4: one block per bin; readlane broadcast + LDS f32 accumulate ----
__global__ void __launch_bounds__(512) gcmc_accum(
    const unsigned int* __restrict__ edges, const int* __restrict__ bin_off,
    const float* __restrict__ wp, const float* __restrict__ ci,
    float* __restrict__ out, int n_dst) {
  __shared__ float acc[(BIN_SIZE + 1) * OUT_DIM];  // +1 scrap row for sentinel
  const int tid = threadIdx.x;
  for (int i = tid; i < (BIN_SIZE + 1) * OUT_DIM; i += 512) acc[i] = 0.f;
  __syncthreads();

  const int bin = blockIdx.x;
  const int start = bin_off[bin];
  const int end = bin_off[bin + 1];
  const int lane = tid & 63;
  const int wid = tid >> 6;
  const unsigned SENT = (unsigned)BIN_SIZE << 20;  // scrap row, src 0

  for (int base = start + wid * 64; base < end; base += 512) {
    const int idx = base + lane;
    const unsigned pk = (idx < end) ? edges[idx] : SENT;
    // readlane at compile-time lane index: no LDS-pipe broadcast, iterations
    // fully independent -> compiler pipelines the 64 loads + 64 ds_adds.
#pragma unroll
    for (int k = 0; k < 64; k += 16) {
#pragma unroll
      for (int kk = 0; kk < 16; ++kk) {
        const unsigned p =
            (unsigned)__builtin_amdgcn_readlane((int)pk, k + kk);
        const int s = (int)(p & 0xFFFFFu);
        const int ld = (int)(p >> 20);
        const float w = wp[s * OUT_DIM + lane];
        atomicAdd(&acc[ld * OUT_DIM + lane], w);
      }
    }
  }
  __syncthreads();

  const int gbase = bin * BIN_SIZE;
  for (int i = tid; i < BIN_SIZE * OUT_DIM; i += 512) {
    const int r = gbase + (i >> 6);
    if (r < n_dst) out[r * OUT_DIM + (i & 63)] = acc[i] * ci[r];
  }
}

// ---- Fallback: global-atomic edge scatter (proven, ~803 us) ----
__global__ void __launch_bounds__(256) gcmc_edge_scatter(
    const int* __restrict__ node_ids, const int* __restrict__ src_idx,
    const int* __restrict__ dst_idx, const float* __restrict__ cj,
    const float* __restrict__ weight, float* __restrict__ out, int n_edges) {
  const int lane = threadIdx.x & 63;
  const int wave = blockIdx.x * (blockDim.x >> 6) + (threadIdx.x >> 6);
  const int nwaves = gridDim.x * (blockDim.x >> 6);
  for (int e = wave; e < n_edges; e += nwaves) {
    const int s = src_idx[e];
    const int d = dst_idx[e];
    const float v = weight[node_ids[s] * OUT_DIM + lane] * cj[s];
    atomicAdd(&out[d * OUT_DIM + lane], v);
  }
}

__global__ void __launch_bounds__(256) gcmc_scale_ci(
    const float* __restrict__ ci, float* __restrict__ out, int n_elems) {
  const int i = blockIdx.x * blockDim.x + threadIdx.x;
  if (i < n_elems) out[i] *= ci[i >> 6];
}

extern "C" void kernel_launch(void* const* d_in, const int* in_sizes, int n_in,
                              void* d_out, int out_size, void* d_ws, size_t ws_size,
                              hipStream_t stream) {
  const int* node_ids = (const int*)d_in[0];
  const int* src_idx  = (const int*)d_in[1];
  const int* dst_idx  = (const int*)d_in[2];
  const float* cj     = (const float*)d_in[3];
  const float* ci     = (const float*)d_in[4];
  const float* weight = (const float*)d_in[5];
  float* out = (float*)d_out;

  const int n_src = in_sizes[0];
  const int n_edges = in_sizes[1];
  const int n_dst = out_size / OUT_DIM;
  const int nbins = (n_dst + BIN_SIZE - 1) >> BIN_BITS;

  // ws layout: wprime[n_src*64] f32 | bin_cnt[nbins] | bin_off[nbins+1] |
  //            bin_pos[nbins] | edges[n_edges]
  const size_t need =
      (size_t)n_src * OUT_DIM * sizeof(float) +
      (size_t)(3 * nbins + 1) * sizeof(int) +
      (size_t)n_edges * sizeof(unsigned int);

  if (ws_size < need || nbins > MAX_BINS) {
    // ---- fallback: proven atomic path ----
    hipMemsetAsync(d_out, 0, (size_t)out_size * sizeof(float), stream);
    gcmc_edge_scatter<<<4096, 256, 0, stream>>>(node_ids, src_idx, dst_idx, cj,
                                                weight, out, n_edges);
    gcmc_scale_ci<<<(out_size + 255) / 256, 256, 0, stream>>>(ci, out,
                                                              out_size);
    return;
  }

  float* wp = (float*)d_ws;
  int* bin_cnt = (int*)(wp + (size_t)n_src * OUT_DIM);
  int* bin_off = bin_cnt + nbins;
  int* bin_pos = bin_off + (nbins + 1);
  unsigned int* edges = (unsigned int*)(bin_pos + nbins);

  hipMemsetAsync(bin_cnt, 0, (size_t)nbins * sizeof(int), stream);

  {
    const int total4 = n_src * (OUT_DIM / 4);
    gcmc_wprime<<<(total4 + 255) / 256, 256, 0, stream>>>(
        node_ids, cj, (const float4*)weight, (float4*)wp, n_src);
  }
  gcmc_hist<<<256, 512, 0, stream>>>(dst_idx, bin_cnt, n_edges, nbins);
  gcmc_scan<<<1, 1024, 0, stream>>>(bin_cnt, bin_off, bin_pos, nbins);
  gcmc_scatter<<<256, 512, 0, stream>>>(dst_idx, src_idx, bin_pos, edges,
                                        n_edges, nbins);
  gcmc_accum<<<nbins, 512, 0, stream>>>(edges, bin_off, wp, ci, out, n_dst);
}

// Round 6
// 1381.210 us; speedup vs baseline: 1.1895x; 1.1084x over previous
//
#include <hip/hip_runtime.h>

// GCMCGraphConv: out[d] = ci[d] * sum_{e: dst[e]==d} weight[node_ids[src[e]]] * cj[src[e]]
// N_SRC = N_DST = 100000, N_EDGES = 3.2M, OUT_DIM = 64.
//
// Pipeline:
//   K0 wprime : W'[s] = weight[node_ids[s]] * cj[s]
//   K1 hist   : per-bin edge counts (bin = dst >> 6)
//   K2 scan   : exclusive scan of bin counts (pair-per-thread, <=2048 bins)
//   K3 scatter: pack (local_dst, src) into bin-grouped order
//   K4 accum  : one block per bin; 16-deep staged wp-row gathers (explicit MLP)
//               + conflict-free LDS f32 atomics; fused ci-scale writeout.
// Fallback (ws too small): global-atomic edge scatter (proven R1).

#define OUT_DIM 64
#define BIN_BITS 6
#define BIN_SIZE 64             // dsts per bin; LDS acc = 65*64*4 = 16.64 KB
#define MAX_BINS 2048

// ---- K0: W'[s][:] = weight[node_ids[s]][:] * cj[s] ----
__global__ void __launch_bounds__(256) gcmc_wprime(
    const int* __restrict__ node_ids, const float* __restrict__ cj,
    const float4* __restrict__ weight4, float4* __restrict__ wp4, int n_src) {
  const int i = blockIdx.x * 256 + threadIdx.x;   // float4 index
  if (i >= n_src * (OUT_DIM / 4)) return;
  const int s = i >> 4;
  const float c = cj[s];
  const int r = node_ids[s];
  float4 w = weight4[r * (OUT_DIM / 4) + (i & 15)];
  w.x *= c; w.y *= c; w.z *= c; w.w *= c;
  wp4[i] = w;
}

// ---- K1: per-bin histogram ----
__global__ void __launch_bounds__(512) gcmc_hist(
    const int* __restrict__ dst_idx, int* __restrict__ bin_cnt,
    int n_edges, int nbins) {
  __shared__ int h[MAX_BINS];
  for (int b = threadIdx.x; b < nbins; b += 512) h[b] = 0;
  __syncthreads();
  for (int e = blockIdx.x * 512 + threadIdx.x; e < n_edges; e += gridDim.x * 512)
    atomicAdd(&h[dst_idx[e] >> BIN_BITS], 1);
  __syncthreads();
  for (int b = threadIdx.x; b < nbins; b += 512) {
    const int c = h[b];
    if (c) atomicAdd(&bin_cnt[b], c);
  }
}

// ---- K2: exclusive scan, pair-per-thread (n <= 2048, single block) ----
__global__ void __launch_bounds__(1024) gcmc_scan(
    const int* __restrict__ cnt, int* __restrict__ off, int* __restrict__ pos,
    int n) {
  __shared__ int lds[1024];
  const int t = threadIdx.x;
  const int i0 = 2 * t, i1 = 2 * t + 1;
  const int a = (i0 < n) ? cnt[i0] : 0;
  const int b = (i1 < n) ? cnt[i1] : 0;
  const int ab = a + b;
  lds[t] = ab;
  __syncthreads();
#pragma unroll
  for (int d = 1; d < 1024; d <<= 1) {
    const int v = (t >= d) ? lds[t - d] : 0;
    __syncthreads();
    lds[t] += v;
    __syncthreads();
  }
  const int excl = lds[t] - ab;   // exclusive sum of pairs before this thread
  if (i0 < n) { off[i0] = excl;     pos[i0] = excl; }
  if (i1 < n) { off[i1] = excl + a; pos[i1] = excl + a; }
  if (t == 1023) off[n] = lds[1023];
}

// ---- K3: scatter packed edges into bin-grouped order ----
// pack = (local_dst << 20) | src   (n_src < 2^20, local_dst < 64)
__global__ void __launch_bounds__(512) gcmc_scatter(
    const int* __restrict__ dst_idx, const int* __restrict__ src_idx,
    int* __restrict__ bin_pos, unsigned int* __restrict__ edges,
    int n_edges, int nbins) {
  __shared__ int h[MAX_BINS];
  for (int b = threadIdx.x; b < nbins; b += 512) h[b] = 0;
  __syncthreads();
  for (int e = blockIdx.x * 512 + threadIdx.x; e < n_edges; e += gridDim.x * 512)
    atomicAdd(&h[dst_idx[e] >> BIN_BITS], 1);
  __syncthreads();
  for (int b = threadIdx.x; b < nbins; b += 512) {
    const int c = h[b];
    h[b] = c ? atomicAdd(&bin_pos[b], c) : 0;
  }
  __syncthreads();
  for (int e = blockIdx.x * 512 + threadIdx.x; e < n_edges; e += gridDim.x * 512) {
    const int d = dst_idx[e];
    const int p = atomicAdd(&h[d >> BIN_BITS], 1);
    edges[p] = ((unsigned)(d & (BIN_SIZE - 1)) << 20) | (unsigned)src_idx[e];
  }
}

// ---- K4: one block per bin; 16-deep staged gathers + LDS accumulate ----
__global__ void __launch_bounds__(512) gcmc_accum(
    const unsigned int* __restrict__ edges, const int* __restrict__ bin_off,
    const float* __restrict__ wp, const float* __restrict__ ci,
    float* __restrict__ out, int n_dst) {
  __shared__ float acc[(BIN_SIZE + 1) * OUT_DIM];  // +1 scrap row for sentinel
  const int tid = threadIdx.x;
  for (int i = tid; i < (BIN_SIZE + 1) * OUT_DIM; i += 512) acc[i] = 0.f;
  __syncthreads();

  const int bin = blockIdx.x;
  const int start = bin_off[bin];
  const int end = bin_off[bin + 1];
  const int lane = tid & 63;
  const int wid = tid >> 6;
  const unsigned SENT = (unsigned)BIN_SIZE << 20;  // scrap row, src 0

  for (int base = start + wid * 64; base < end; base += 512) {
    const int idx = base + lane;
    const unsigned pk = (idx < end) ? edges[idx] : SENT;
    // Stage 16 independent wp-row loads into registers (static indices ->
    // stays in VGPRs), THEN do the 16 LDS adds. Explicit MLP = 16 per wave.
#pragma unroll
    for (int k = 0; k < 64; k += 16) {
      float wbuf[16];
#pragma unroll
      for (int j = 0; j < 16; ++j) {
        const unsigned p =
            (unsigned)__builtin_amdgcn_readlane((int)pk, k + j);
        wbuf[j] = wp[(p & 0xFFFFFu) * OUT_DIM + lane];
      }
#pragma unroll
      for (int j = 0; j < 16; ++j) {
        const unsigned p =
            (unsigned)__builtin_amdgcn_readlane((int)pk, k + j);
        atomicAdd(&acc[(p >> 20) * OUT_DIM + lane], wbuf[j]);
      }
    }
  }
  __syncthreads();

  const int gbase = bin * BIN_SIZE;
  for (int i = tid; i < BIN_SIZE * OUT_DIM; i += 512) {
    const int r = gbase + (i >> 6);
    if (r < n_dst) out[r * OUT_DIM + (i & 63)] = acc[i] * ci[r];
  }
}

// ---- Fallback: global-atomic edge scatter (proven, ~803 us) ----
__global__ void __launch_bounds__(256) gcmc_edge_scatter(
    const int* __restrict__ node_ids, const int* __restrict__ src_idx,
    const int* __restrict__ dst_idx, const float* __restrict__ cj,
    const float* __restrict__ weight, float* __restrict__ out, int n_edges) {
  const int lane = threadIdx.x & 63;
  const int wave = blockIdx.x * (blockDim.x >> 6) + (threadIdx.x >> 6);
  const int nwaves = gridDim.x * (blockDim.x >> 6);
  for (int e = wave; e < n_edges; e += nwaves) {
    const int s = src_idx[e];
    const int d = dst_idx[e];
    const float v = weight[node_ids[s] * OUT_DIM + lane] * cj[s];
    atomicAdd(&out[d * OUT_DIM + lane], v);
  }
}

__global__ void __launch_bounds__(256) gcmc_scale_ci(
    const float* __restrict__ ci, float* __restrict__ out, int n_elems) {
  const int i = blockIdx.x * blockDim.x + threadIdx.x;
  if (i < n_elems) out[i] *= ci[i >> 6];
}

extern "C" void kernel_launch(void* const* d_in, const int* in_sizes, int n_in,
                              void* d_out, int out_size, void* d_ws, size_t ws_size,
                              hipStream_t stream) {
  const int* node_ids = (const int*)d_in[0];
  const int* src_idx  = (const int*)d_in[1];
  const int* dst_idx  = (const int*)d_in[2];
  const float* cj     = (const float*)d_in[3];
  const float* ci     = (const float*)d_in[4];
  const float* weight = (const float*)d_in[5];
  float* out = (float*)d_out;

  const int n_src = in_sizes[0];
  const int n_edges = in_sizes[1];
  const int n_dst = out_size / OUT_DIM;
  const int nbins = (n_dst + BIN_SIZE - 1) >> BIN_BITS;   // 1563 for 100k

  // ws layout: wprime[n_src*64] f32 | bin_cnt[nbins] | bin_off[nbins+1] |
  //            bin_pos[nbins] | edges[n_edges]
  const size_t need =
      (size_t)n_src * OUT_DIM * sizeof(float) +
      (size_t)(3 * nbins + 1) * sizeof(int) +
      (size_t)n_edges * sizeof(unsigned int);

  if (ws_size < need || nbins > MAX_BINS) {
    hipMemsetAsync(d_out, 0, (size_t)out_size * sizeof(float), stream);
    gcmc_edge_scatter<<<4096, 256, 0, stream>>>(node_ids, src_idx, dst_idx, cj,
                                                weight, out, n_edges);
    gcmc_scale_ci<<<(out_size + 255) / 256, 256, 0, stream>>>(ci, out,
                                                              out_size);
    return;
  }

  float* wp = (float*)d_ws;
  int* bin_cnt = (int*)(wp + (size_t)n_src * OUT_DIM);
  int* bin_off = bin_cnt + nbins;
  int* bin_pos = bin_off + (nbins + 1);
  unsigned int* edges = (unsigned int*)(bin_pos + nbins);

  hipMemsetAsync(bin_cnt, 0, (size_t)nbins * sizeof(int), stream);

  {
    const int total4 = n_src * (OUT_DIM / 4);
    gcmc_wprime<<<(total4 + 255) / 256, 256, 0, stream>>>(
        node_ids, cj, (const float4*)weight, (float4*)wp, n_src);
  }
  gcmc_hist<<<256, 512, 0, stream>>>(dst_idx, bin_cnt, n_edges, nbins);
  gcmc_scan<<<1, 1024, 0, stream>>>(bin_cnt, bin_off, bin_pos, nbins);
  gcmc_scatter<<<256, 512, 0, stream>>>(dst_idx, src_idx, bin_pos, edges,
                                        n_edges, nbins);
  gcmc_accum<<<nbins, 512, 0, stream>>>(edges, bin_off, wp, ci, out, n_dst);
}

// Round 7
// 292.926 us; speedup vs baseline: 5.6089x; 4.7152x over previous
//
#include <hip/hip_runtime.h>

// GCMCGraphConv: out[d] = ci[d] * sum_{e: dst[e]==d} weight[node_ids[src[e]]] * cj[src[e]]
// N_SRC = N_DST = 100000, N_EDGES = 3.2M, OUT_DIM = 64.
//
// Pipeline:
//   K0 wprime : W'[s] = weight[node_ids[s]] * cj[s]
//   K1 hist   : per-bin edge counts (bin = dst >> 6)
//   K2 scan   : exclusive scan of bin counts (pair-per-thread, <=2048 bins)
//   K3 scatter: pack (local_dst<<20 | src) into bin-grouped order
//   K4 sortgather: per bin: LDS counting-sort by local dst, then per-dst
//       register accumulation of wp rows (no f32 atomics anywhere), fused ci.
// Fallback (ws too small / shape limits): global-atomic edge scatter (R1).

#define OUT_DIM 64
#define BIN_BITS 6
#define BIN_SIZE 64             // dsts per bin
#define MAX_BINS 2048
#define CAP 4096                // edges sorted per chunk in LDS (bin avg ~2048)

// ---- K0: W'[s][:] = weight[node_ids[s]][:] * cj[s] ----
__global__ void __launch_bounds__(256) gcmc_wprime(
    const int* __restrict__ node_ids, const float* __restrict__ cj,
    const float4* __restrict__ weight4, float4* __restrict__ wp4, int n_src) {
  const int i = blockIdx.x * 256 + threadIdx.x;   // float4 index
  if (i >= n_src * (OUT_DIM / 4)) return;
  const int s = i >> 4;
  const float c = cj[s];
  const int r = node_ids[s];
  float4 w = weight4[r * (OUT_DIM / 4) + (i & 15)];
  w.x *= c; w.y *= c; w.z *= c; w.w *= c;
  wp4[i] = w;
}

// ---- K1: per-bin histogram ----
__global__ void __launch_bounds__(1024) gcmc_hist(
    const int* __restrict__ dst_idx, int* __restrict__ bin_cnt,
    int n_edges, int nbins) {
  __shared__ int h[MAX_BINS];
  for (int b = threadIdx.x; b < nbins; b += 1024) h[b] = 0;
  __syncthreads();
  for (int e = blockIdx.x * 1024 + threadIdx.x; e < n_edges;
       e += gridDim.x * 1024)
    atomicAdd(&h[dst_idx[e] >> BIN_BITS], 1);
  __syncthreads();
  for (int b = threadIdx.x; b < nbins; b += 1024) {
    const int c = h[b];
    if (c) atomicAdd(&bin_cnt[b], c);
  }
}

// ---- K2: exclusive scan, pair-per-thread (n <= 2048, single block) ----
__global__ void __launch_bounds__(1024) gcmc_scan(
    const int* __restrict__ cnt, int* __restrict__ off, int* __restrict__ pos,
    int n) {
  __shared__ int lds[1024];
  const int t = threadIdx.x;
  const int i0 = 2 * t, i1 = 2 * t + 1;
  const int a = (i0 < n) ? cnt[i0] : 0;
  const int b = (i1 < n) ? cnt[i1] : 0;
  const int ab = a + b;
  lds[t] = ab;
  __syncthreads();
#pragma unroll
  for (int d = 1; d < 1024; d <<= 1) {
    const int v = (t >= d) ? lds[t - d] : 0;
    __syncthreads();
    lds[t] += v;
    __syncthreads();
  }
  const int excl = lds[t] - ab;
  if (i0 < n) { off[i0] = excl;     pos[i0] = excl; }
  if (i1 < n) { off[i1] = excl + a; pos[i1] = excl + a; }
  if (t == 1023) off[n] = lds[1023];
}

// ---- K3: scatter packed edges into bin-grouped order ----
__global__ void __launch_bounds__(1024) gcmc_scatter(
    const int* __restrict__ dst_idx, const int* __restrict__ src_idx,
    int* __restrict__ bin_pos, unsigned int* __restrict__ edges,
    int n_edges, int nbins) {
  __shared__ int h[MAX_BINS];
  for (int b = threadIdx.x; b < nbins; b += 1024) h[b] = 0;
  __syncthreads();
  for (int e = blockIdx.x * 1024 + threadIdx.x; e < n_edges;
       e += gridDim.x * 1024)
    atomicAdd(&h[dst_idx[e] >> BIN_BITS], 1);
  __syncthreads();
  for (int b = threadIdx.x; b < nbins; b += 1024) {
    const int c = h[b];
    h[b] = c ? atomicAdd(&bin_pos[b], c) : 0;
  }
  __syncthreads();
  for (int e = blockIdx.x * 1024 + threadIdx.x; e < n_edges;
       e += gridDim.x * 1024) {
    const int d = dst_idx[e];
    const int p = atomicAdd(&h[d >> BIN_BITS], 1);
    edges[p] = ((unsigned)(d & (BIN_SIZE - 1)) << 20) | (unsigned)src_idx[e];
  }
}

// ---- K4: per-bin counting sort in LDS + per-dst register gather ----
__global__ void __launch_bounds__(512) gcmc_sortgather(
    const unsigned int* __restrict__ edges, const int* __restrict__ bin_off,
    const float* __restrict__ wp, const float* __restrict__ ci,
    float* __restrict__ out, int n_dst) {
  __shared__ unsigned int sorted[CAP + 64];  // srcs, dst-sorted; +64 overread pad
  __shared__ int hist[BIN_SIZE];
  __shared__ int offs[BIN_SIZE + 1];
  __shared__ int curs[BIN_SIZE];

  const int bin = blockIdx.x;
  const int start = bin_off[bin];
  const int total = bin_off[bin + 1] - start;
  const int tid = threadIdx.x;
  const int lane = tid & 63;
  const int wid = tid >> 6;
  const int gd0 = bin << BIN_BITS;

  int nch = (total + CAP - 1) / CAP;
  if (nch == 0) nch = 1;  // still write zero rows

  for (int c = 0; c < nch; ++c) {
    const int cbase = start + c * CAP;
    const int cnt = min(CAP, start + total - cbase);  // >= 0

    if (tid < BIN_SIZE) hist[tid] = 0;
    __syncthreads();
    // hist over this chunk (LDS u32 atomics: ~32 wave-ops per chunk)
    for (int i = tid; i < cnt; i += 512)
      atomicAdd(&hist[edges[cbase + i] >> 20], 1);
    __syncthreads();
    // scan 64 counters with one wave (shfl)
    if (wid == 0) {
      const int v = hist[lane];
      int incl = v;
#pragma unroll
      for (int d = 1; d < 64; d <<= 1) {
        const int t = __shfl_up(incl, d);
        if (lane >= d) incl += t;
      }
      offs[lane] = incl - v;
      curs[lane] = incl - v;
      if (lane == 63) offs[64] = incl;
    }
    __syncthreads();
    // cursor-scatter srcs into dst-sorted LDS order
    for (int i = tid; i < cnt; i += 512) {
      const unsigned p = edges[cbase + i];
      const int pos = atomicAdd(&curs[p >> 20], 1);
      sorted[pos] = p & 0xFFFFFu;
    }
    __syncthreads();

    // gather: wave wid owns local dsts wid, wid+8, ...
    for (int ld = wid; ld < BIN_SIZE; ld += 8) {
      const int gd = gd0 + ld;
      if (gd >= n_dst) break;
      const int o0 = __builtin_amdgcn_readfirstlane(offs[ld]);
      const int o1 = __builtin_amdgcn_readfirstlane(offs[ld + 1]);
      float acc = 0.f;
      for (int base = o0; base < o1; base += 64) {
        const int m = min(64, o1 - base);
        const int vsrc = (int)sorted[base + lane];  // 1 ds_read / 64 edges
        int k = 0;
        for (; k + 4 <= m; k += 4) {
          const int s0 = __builtin_amdgcn_readlane(vsrc, k);
          const int s1 = __builtin_amdgcn_readlane(vsrc, k + 1);
          const int s2 = __builtin_amdgcn_readlane(vsrc, k + 2);
          const int s3 = __builtin_amdgcn_readlane(vsrc, k + 3);
          const float w0 = wp[(unsigned)s0 * 64u + lane];
          const float w1 = wp[(unsigned)s1 * 64u + lane];
          const float w2 = wp[(unsigned)s2 * 64u + lane];
          const float w3 = wp[(unsigned)s3 * 64u + lane];
          acc += w0 + w1 + w2 + w3;
        }
        for (; k < m; ++k) {
          const int s = __builtin_amdgcn_readlane(vsrc, k);
          acc += wp[(unsigned)s * 64u + lane];
        }
      }
      float* po = &out[(size_t)gd * OUT_DIM + lane];
      float v = acc;
      if (c > 0) v += *po;             // accumulate across chunks (rare path)
      if (c == nch - 1) v *= ci[gd];   // final scale
      *po = v;
    }
    __syncthreads();  // protect LDS before next chunk
  }
}

// ---- Fallback: global-atomic edge scatter (proven, ~803 us) ----
__global__ void __launch_bounds__(256) gcmc_edge_scatter(
    const int* __restrict__ node_ids, const int* __restrict__ src_idx,
    const int* __restrict__ dst_idx, const float* __restrict__ cj,
    const float* __restrict__ weight, float* __restrict__ out, int n_edges) {
  const int lane = threadIdx.x & 63;
  const int wave = blockIdx.x * (blockDim.x >> 6) + (threadIdx.x >> 6);
  const int nwaves = gridDim.x * (blockDim.x >> 6);
  for (int e = wave; e < n_edges; e += nwaves) {
    const int s = src_idx[e];
    const int d = dst_idx[e];
    const float v = weight[node_ids[s] * OUT_DIM + lane] * cj[s];
    atomicAdd(&out[d * OUT_DIM + lane], v);
  }
}

__global__ void __launch_bounds__(256) gcmc_scale_ci(
    const float* __restrict__ ci, float* __restrict__ out, int n_elems) {
  const int i = blockIdx.x * blockDim.x + threadIdx.x;
  if (i < n_elems) out[i] *= ci[i >> 6];
}

extern "C" void kernel_launch(void* const* d_in, const int* in_sizes, int n_in,
                              void* d_out, int out_size, void* d_ws, size_t ws_size,
                              hipStream_t stream) {
  const int* node_ids = (const int*)d_in[0];
  const int* src_idx  = (const int*)d_in[1];
  const int* dst_idx  = (const int*)d_in[2];
  const float* cj     = (const float*)d_in[3];
  const float* ci     = (const float*)d_in[4];
  const float* weight = (const float*)d_in[5];
  float* out = (float*)d_out;

  const int n_src = in_sizes[0];
  const int n_edges = in_sizes[1];
  const int n_dst = out_size / OUT_DIM;
  const int nbins = (n_dst + BIN_SIZE - 1) >> BIN_BITS;  // 1563 for 100k

  // ws layout: wprime[n_src*64] f32 | bin_cnt[nbins] | bin_off[nbins+1] |
  //            bin_pos[nbins] | edges[n_edges]
  const size_t need =
      (size_t)n_src * OUT_DIM * sizeof(float) +
      (size_t)(3 * nbins + 1) * sizeof(int) +
      (size_t)n_edges * sizeof(unsigned int);

  if (ws_size < need || nbins > MAX_BINS || n_src >= (1 << 20)) {
    hipMemsetAsync(d_out, 0, (size_t)out_size * sizeof(float), stream);
    gcmc_edge_scatter<<<4096, 256, 0, stream>>>(node_ids, src_idx, dst_idx, cj,
                                                weight, out, n_edges);
    gcmc_scale_ci<<<(out_size + 255) / 256, 256, 0, stream>>>(ci, out,
                                                              out_size);
    return;
  }

  float* wp = (float*)d_ws;
  int* bin_cnt = (int*)(wp + (size_t)n_src * OUT_DIM);
  int* bin_off = bin_cnt + nbins;
  int* bin_pos = bin_off + (nbins + 1);
  unsigned int* edges = (unsigned int*)(bin_pos + nbins);

  hipMemsetAsync(bin_cnt, 0, (size_t)nbins * sizeof(int), stream);

  {
    const int total4 = n_src * (OUT_DIM / 4);
    gcmc_wprime<<<(total4 + 255) / 256, 256, 0, stream>>>(
        node_ids, cj, (const float4*)weight, (float4*)wp, n_src);
  }
  gcmc_hist<<<256, 1024, 0, stream>>>(dst_idx, bin_cnt, n_edges, nbins);
  gcmc_scan<<<1, 1024, 0, stream>>>(bin_cnt, bin_off, bin_pos, nbins);
  gcmc_scatter<<<256, 1024, 0, stream>>>(dst_idx, src_idx, bin_pos, edges,
                                         n_edges, nbins);
  gcmc_sortgather<<<nbins, 512, 0, stream>>>(edges, bin_off, wp, ci, out,
                                             n_dst);
}

// Round 12
// 257.239 us; speedup vs baseline: 6.3870x; 1.1387x over previous
//
#include <hip/hip_runtime.h>

// GCMCGraphConv: out[d] = ci[d] * sum_{e: dst[e]==d} weight[node_ids[src[e]]] * cj[src[e]]
// N_SRC = N_DST = 100000, N_EDGES = 3.2M, OUT_DIM = 64.
//
// R12 = verbatim resubmit of R11 (GPU-acquisition timeout; source never ran).
// R11 = R7's proven-running skeleton + ONE change: W' table stored as bf16
// (halves the dominant sortgather gather traffic). R8/R10's restructured
// single-pass binning is deferred — isolating the bf16 delta on a skeleton
// that has executed successfully three times (R5/R6/R7).
//
// Pipeline:
//   K0 wprime : W'[s] = bf16(weight[node_ids[s]] * cj[s])   (12.8 MB table)
//   K1 hist   : per-bin edge counts (bin = dst >> 6)
//   K2 scan   : exclusive scan of bin counts (pair-per-thread, <=2048 bins)
//   K3 scatter: pack (local_dst<<20 | src) into bin-grouped order
//   K4 sortgather: per bin: LDS counting-sort by local dst, then per-dst
//       register accumulation of bf16 W' rows (f32 accum), fused ci scale.
// Fallback (ws too small / shape limits): global-atomic edge scatter (R1).

#define OUT_DIM 64
#define BIN_BITS 6
#define BIN_SIZE 64             // dsts per bin
#define MAX_BINS 2048
#define CAP 4096                // edges sorted per chunk in LDS (bin avg ~2048)

__device__ inline unsigned short f2bf(float f) {
  union { float f; unsigned u; } v; v.f = f;
  const unsigned r = (v.u + 0x7FFFu + ((v.u >> 16) & 1u)) >> 16;  // RNE
  return (unsigned short)r;
}
__device__ inline float bf2f(unsigned short h) {
  union { unsigned u; float f; } v; v.u = ((unsigned)h) << 16;
  return v.f;
}

// ---- K0: W'[s][:] = bf16(weight[node_ids[s]][:] * cj[s]) ----
__global__ void __launch_bounds__(256) gcmc_wprime(
    const int* __restrict__ node_ids, const float* __restrict__ cj,
    const float4* __restrict__ weight4, unsigned short* __restrict__ wp16,
    int n_src) {
  const int i = blockIdx.x * 256 + threadIdx.x;   // float4 index
  if (i >= n_src * (OUT_DIM / 4)) return;
  const int s = i >> 4;
  const float c = cj[s];
  const int r = node_ids[s];
  const float4 w = weight4[r * (OUT_DIM / 4) + (i & 15)];
  ushort4 o;
  o.x = f2bf(w.x * c); o.y = f2bf(w.y * c);
  o.z = f2bf(w.z * c); o.w = f2bf(w.w * c);
  *(ushort4*)&wp16[(size_t)s * OUT_DIM + (i & 15) * 4] = o;
}

// ---- K1: per-bin histogram ----
__global__ void __launch_bounds__(1024) gcmc_hist(
    const int* __restrict__ dst_idx, int* __restrict__ bin_cnt,
    int n_edges, int nbins) {
  __shared__ int h[MAX_BINS];
  for (int b = threadIdx.x; b < nbins; b += 1024) h[b] = 0;
  __syncthreads();
  for (int e = blockIdx.x * 1024 + threadIdx.x; e < n_edges;
       e += gridDim.x * 1024)
    atomicAdd(&h[dst_idx[e] >> BIN_BITS], 1);
  __syncthreads();
  for (int b = threadIdx.x; b < nbins; b += 1024) {
    const int c = h[b];
    if (c) atomicAdd(&bin_cnt[b], c);
  }
}

// ---- K2: exclusive scan, pair-per-thread (n <= 2048, single block) ----
__global__ void __launch_bounds__(1024) gcmc_scan(
    const int* __restrict__ cnt, int* __restrict__ off, int* __restrict__ pos,
    int n) {
  __shared__ int lds[1024];
  const int t = threadIdx.x;
  const int i0 = 2 * t, i1 = 2 * t + 1;
  const int a = (i0 < n) ? cnt[i0] : 0;
  const int b = (i1 < n) ? cnt[i1] : 0;
  const int ab = a + b;
  lds[t] = ab;
  __syncthreads();
#pragma unroll
  for (int d = 1; d < 1024; d <<= 1) {
    const int v = (t >= d) ? lds[t - d] : 0;
    __syncthreads();
    lds[t] += v;
    __syncthreads();
  }
  const int excl = lds[t] - ab;
  if (i0 < n) { off[i0] = excl;     pos[i0] = excl; }
  if (i1 < n) { off[i1] = excl + a; pos[i1] = excl + a; }
  if (t == 1023) off[n] = lds[1023];
}

// ---- K3: scatter packed edges into bin-grouped order ----
// pack = (local_dst << 20) | src   (n_src < 2^20, local_dst < 64)
__global__ void __launch_bounds__(1024) gcmc_scatter(
    const int* __restrict__ dst_idx, const int* __restrict__ src_idx,
    int* __restrict__ bin_pos, unsigned int* __restrict__ edges,
    int n_edges, int nbins) {
  __shared__ int h[MAX_BINS];
  for (int b = threadIdx.x; b < nbins; b += 1024) h[b] = 0;
  __syncthreads();
  for (int e = blockIdx.x * 1024 + threadIdx.x; e < n_edges;
       e += gridDim.x * 1024)
    atomicAdd(&h[dst_idx[e] >> BIN_BITS], 1);
  __syncthreads();
  for (int b = threadIdx.x; b < nbins; b += 1024) {
    const int c = h[b];
    h[b] = c ? atomicAdd(&bin_pos[b], c) : 0;
  }
  __syncthreads();
  for (int e = blockIdx.x * 1024 + threadIdx.x; e < n_edges;
       e += gridDim.x * 1024) {
    const int d = dst_idx[e];
    const int p = atomicAdd(&h[d >> BIN_BITS], 1);
    edges[p] = ((unsigned)(d & (BIN_SIZE - 1)) << 20) | (unsigned)src_idx[e];
  }
}

// ---- K4: per-bin counting sort in LDS + per-dst register gather ----
__global__ void __launch_bounds__(512) gcmc_sortgather(
    const unsigned int* __restrict__ edges, const int* __restrict__ bin_off,
    const unsigned short* __restrict__ wp16, const float* __restrict__ ci,
    float* __restrict__ out, int n_dst) {
  __shared__ unsigned int sorted[CAP + 64];  // srcs, dst-sorted; +64 overread pad
  __shared__ int hist[BIN_SIZE];
  __shared__ int offs[BIN_SIZE + 1];
  __shared__ int curs[BIN_SIZE];

  const int bin = blockIdx.x;
  const int start = bin_off[bin];
  const int total = bin_off[bin + 1] - start;
  const int tid = threadIdx.x;
  const int lane = tid & 63;
  const int wid = tid >> 6;
  const int gd0 = bin << BIN_BITS;

  int nch = (total + CAP - 1) / CAP;
  if (nch == 0) nch = 1;  // still write zero rows

  for (int c = 0; c < nch; ++c) {
    const int cbase = start + c * CAP;
    const int cnt = min(CAP, start + total - cbase);  // >= 0

    if (tid < BIN_SIZE) hist[tid] = 0;
    __syncthreads();
    for (int i = tid; i < cnt; i += 512)
      atomicAdd(&hist[edges[cbase + i] >> 20], 1);
    __syncthreads();
    if (wid == 0) {  // scan 64 counters with one wave
      const int v = hist[lane];
      int incl = v;
#pragma unroll
      for (int d = 1; d < 64; d <<= 1) {
        const int t = __shfl_up(incl, d);
        if (lane >= d) incl += t;
      }
      offs[lane] = incl - v;
      curs[lane] = incl - v;
      if (lane == 63) offs[64] = incl;
    }
    __syncthreads();
    for (int i = tid; i < cnt; i += 512) {
      const unsigned p = edges[cbase + i];
      const int pos = atomicAdd(&curs[p >> 20], 1);
      sorted[pos] = p & 0xFFFFFu;
    }
    __syncthreads();

    // gather: wave wid owns local dsts wid, wid+8, ...
    for (int ld = wid; ld < BIN_SIZE; ld += 8) {
      const int gd = gd0 + ld;
      if (gd >= n_dst) break;
      const int o0 = __builtin_amdgcn_readfirstlane(offs[ld]);
      const int o1 = __builtin_amdgcn_readfirstlane(offs[ld + 1]);
      float acc = 0.f;
      for (int base = o0; base < o1; base += 64) {
        const int m = min(64, o1 - base);
        const int vsrc = (int)sorted[base + lane];  // 1 ds_read per 64 edges
        int k = 0;
        for (; k + 4 <= m; k += 4) {
          const int s0 = __builtin_amdgcn_readlane(vsrc, k);
          const int s1 = __builtin_amdgcn_readlane(vsrc, k + 1);
          const int s2 = __builtin_amdgcn_readlane(vsrc, k + 2);
          const int s3 = __builtin_amdgcn_readlane(vsrc, k + 3);
          const float w0 = bf2f(wp16[(size_t)(unsigned)s0 * 64u + lane]);
          const float w1 = bf2f(wp16[(size_t)(unsigned)s1 * 64u + lane]);
          const float w2 = bf2f(wp16[(size_t)(unsigned)s2 * 64u + lane]);
          const float w3 = bf2f(wp16[(size_t)(unsigned)s3 * 64u + lane]);
          acc += w0 + w1 + w2 + w3;
        }
        for (; k < m; ++k) {
          const int s = __builtin_amdgcn_readlane(vsrc, k);
          acc += bf2f(wp16[(size_t)(unsigned)s * 64u + lane]);
        }
      }
      float* po = &out[(size_t)gd * OUT_DIM + lane];
      float v = acc;
      if (c > 0) v += *po;             // accumulate across chunks (rare path)
      if (c == nch - 1) v *= ci[gd];   // final scale
      *po = v;
    }
    __syncthreads();  // protect LDS before next chunk
  }
}

// ---- Fallback: global-atomic edge scatter (proven, ~803 us) ----
__global__ void __launch_bounds__(256) gcmc_edge_scatter(
    const int* __restrict__ node_ids, const int* __restrict__ src_idx,
    const int* __restrict__ dst_idx, const float* __restrict__ cj,
    const float* __restrict__ weight, float* __restrict__ out, int n_edges) {
  const int lane = threadIdx.x & 63;
  const int wave = blockIdx.x * (blockDim.x >> 6) + (threadIdx.x >> 6);
  const int nwaves = gridDim.x * (blockDim.x >> 6);
  for (int e = wave; e < n_edges; e += nwaves) {
    const int s = src_idx[e];
    const int d = dst_idx[e];
    const float v = weight[node_ids[s] * OUT_DIM + lane] * cj[s];
    atomicAdd(&out[d * OUT_DIM + lane], v);
  }
}

__global__ void __launch_bounds__(256) gcmc_scale_ci(
    const float* __restrict__ ci, float* __restrict__ out, int n_elems) {
  const int i = blockIdx.x * blockDim.x + threadIdx.x;
  if (i < n_elems) out[i] *= ci[i >> 6];
}

extern "C" void kernel_launch(void* const* d_in, const int* in_sizes, int n_in,
                              void* d_out, int out_size, void* d_ws, size_t ws_size,
                              hipStream_t stream) {
  const int* node_ids = (const int*)d_in[0];
  const int* src_idx  = (const int*)d_in[1];
  const int* dst_idx  = (const int*)d_in[2];
  const float* cj     = (const float*)d_in[3];
  const float* ci     = (const float*)d_in[4];
  const float* weight = (const float*)d_in[5];
  float* out = (float*)d_out;

  const int n_src = in_sizes[0];
  const int n_edges = in_sizes[1];
  const int n_dst = out_size / OUT_DIM;
  const int nbins = (n_dst + BIN_SIZE - 1) >> BIN_BITS;  // 1563 for 100k

  // ws layout: wp16[n_src*64] bf16 | bin_cnt[nbins] | bin_off[nbins+1] |
  //            bin_pos[nbins] | edges[n_edges]        (~25.7 MB total)
  const size_t need =
      (size_t)n_src * OUT_DIM * sizeof(unsigned short) +
      (size_t)(3 * nbins + 1) * sizeof(int) +
      (size_t)n_edges * sizeof(unsigned int);

  if (ws_size < need || nbins > MAX_BINS || n_src >= (1 << 20)) {
    hipMemsetAsync(d_out, 0, (size_t)out_size * sizeof(float), stream);
    gcmc_edge_scatter<<<4096, 256, 0, stream>>>(node_ids, src_idx, dst_idx, cj,
                                                weight, out, n_edges);
    gcmc_scale_ci<<<(out_size + 255) / 256, 256, 0, stream>>>(ci, out,
                                                              out_size);
    return;
  }

  unsigned short* wp16 = (unsigned short*)d_ws;
  int* bin_cnt = (int*)(wp16 + (size_t)n_src * OUT_DIM);
  int* bin_off = bin_cnt + nbins;
  int* bin_pos = bin_off + (nbins + 1);
  unsigned int* edges = (unsigned int*)(bin_pos + nbins);

  hipMemsetAsync(bin_cnt, 0, (size_t)nbins * sizeof(int), stream);

  {
    const int total4 = n_src * (OUT_DIM / 4);
    gcmc_wprime<<<(total4 + 255) / 256, 256, 0, stream>>>(
        node_ids, cj, (const float4*)weight, wp16, n_src);
  }
  gcmc_hist<<<256, 1024, 0, stream>>>(dst_idx, bin_cnt, n_edges, nbins);
  gcmc_scan<<<1, 1024, 0, stream>>>(bin_cnt, bin_off, bin_pos, nbins);
  gcmc_scatter<<<256, 1024, 0, stream>>>(dst_idx, src_idx, bin_pos, edges,
                                         n_edges, nbins);
  gcmc_sortgather<<<nbins, 512, 0, stream>>>(edges, bin_off, wp16, ci, out,
                                             n_dst);
}